// Round 7
// baseline (161.374 us; speedup 1.0000x reference)
//
#include <hip/hip_runtime.h>

// Causal self-attention: B=1, T=4096, C=768, H=12, hd=64
// f32 in/out, bf16 MFMA compute internally. Flash-decoding s-split.
// R7: GEMM double-buffered staging (counted vmcnt(8), raw barriers, loads in
// flight across barriers) + bijective XCD swizzle. attn unchanged from R6.

typedef short bf16x8 __attribute__((ext_vector_type(8)));
typedef float f32x4 __attribute__((ext_vector_type(4)));

#define T_SEQ 4096
#define C_DIM 768
#define NH 12
#define HD 64

__device__ __forceinline__ unsigned short f2bf(float f) {
  union { float f; unsigned u; } v; v.f = f;
  unsigned r = v.u + 0x7FFFu + ((v.u >> 16) & 1u);
  return (unsigned short)(r >> 16);
}
__device__ __forceinline__ float bf2f(unsigned short u) {
  union { unsigned u; float f; } v; v.u = ((unsigned)u) << 16;
  return v.f;
}
__device__ __forceinline__ unsigned cvtpk(float a, float b) {
  unsigned r;
  asm("v_cvt_pk_bf16_f32 %0, %1, %2" : "=v"(r) : "v"(a), "v"(b));
  return r;
}

#define GLD16(g, l) __builtin_amdgcn_global_load_lds( \
    (const __attribute__((address_space(1))) void*)(g), \
    (__attribute__((address_space(3))) void*)(l), 16, 0, 0)

// ---------------- f32 -> bf16 convert (vectorized) ----------------
__global__ void conv_bf16(const float* __restrict__ in, unsigned short* __restrict__ out, int n) {
  int i = (blockIdx.x * blockDim.x + threadIdx.x) * 4;
  if (i + 3 < n) {
    float4 v = *reinterpret_cast<const float4*>(in + i);
    ushort4 o;
    o.x = f2bf(v.x); o.y = f2bf(v.y); o.z = f2bf(v.z); o.w = f2bf(v.w);
    *reinterpret_cast<ushort4*>(out + i) = o;
  }
}

// ---------------- transpose f32 [R][Cc] -> bf16 [Cc][R] ----------------
__global__ void transpose_bf16(const float* __restrict__ in, unsigned short* __restrict__ out,
                               int R, int Cc) {
  __shared__ float tile[32][33];
  int bx = blockIdx.x * 32;
  int by = blockIdx.y * 32;
  int tx = threadIdx.x & 31, ty = threadIdx.x >> 5;
#pragma unroll
  for (int i = 0; i < 32; i += 8)
    tile[ty + i][tx] = in[(size_t)(by + ty + i) * Cc + bx + tx];
  __syncthreads();
#pragma unroll
  for (int i = 0; i < 32; i += 8)
    out[(size_t)(bx + ty + i) * R + by + tx] = f2bf(tile[tx][ty + i]);
}

// ---------------- BT-GEMM: A[M][K] bf16 @ Bt[N][K] bf16 ----------------
// 1-D grid (XCD-swizzled), double-buffered LDS, counted vmcnt.
template <int MODE>
__global__ __launch_bounds__(256, 2)
void gemm_bt(const unsigned short* __restrict__ A,
             const unsigned short* __restrict__ Bt,
             void* __restrict__ out0,
             unsigned short* __restrict__ Kout,
             unsigned short* __restrict__ Vt,
             int M, int N, int K) {
  __shared__ __align__(16) unsigned short As[2][128 * 64];
  __shared__ __align__(16) unsigned short Bs[2][128 * 64];
  const int nbn = N / 128;
  const int nwg = (M / 128) * nbn;
  // bijective XCD swizzle (nwg % 8 == 0 for all our shapes: 576, 192)
  const int cpx = nwg >> 3;
  const int swz = ((int)blockIdx.x & 7) * cpx + ((int)blockIdx.x >> 3);
  const int bm = swz / nbn, bn = swz % nbn;

  const int tid = threadIdx.x;
  const int wid = tid >> 6, lane = tid & 63;
  const int wr = wid >> 1, wc = wid & 1;
  const int lr = lane & 15;
  const int lk8 = (lane >> 4) * 8;
  const int rsub = lane >> 3, csub = (lane & 7) * 8;

  f32x4 acc[4][4] = {};
  const int nk = K / 64;

  // stage tile kt into buffer buf: 8 global_load_lds per wave (4 A + 4 B)
  auto STAGE = [&](int kt, int buf) {
    const unsigned short* gA = A + (size_t)(bm * 128) * K + kt * 64;
    const unsigned short* gB = Bt + (size_t)(bn * 128) * K + kt * 64;
#pragma unroll
    for (int c = 0; c < 4; ++c) {
      int seg = wid * 4 + c;
      int row = seg * 8 + rsub;
      GLD16(gA + (size_t)row * K + csub, (char*)As[buf] + seg * 1024);
      GLD16(gB + (size_t)row * K + csub, (char*)Bs[buf] + seg * 1024);
    }
  };

  STAGE(0, 0);
  int cur = 0;
  for (int kt = 0; kt < nk; ++kt) {
    if (kt + 1 < nk) {
      STAGE(kt + 1, cur ^ 1);
      asm volatile("s_waitcnt vmcnt(8)" ::: "memory");  // cur tile's 8 loads done
    } else {
      asm volatile("s_waitcnt vmcnt(0)" ::: "memory");
    }
    __builtin_amdgcn_s_barrier();
#pragma unroll
    for (int kk = 0; kk < 2; ++kk) {
      bf16x8 a[4], b[4];
      int lk = kk * 32 + lk8;
#pragma unroll
      for (int m = 0; m < 4; ++m)
        a[m] = *reinterpret_cast<const bf16x8*>(&As[cur][(wr * 64 + m * 16 + lr) * 64 + lk]);
#pragma unroll
      for (int n = 0; n < 4; ++n)
        b[n] = *reinterpret_cast<const bf16x8*>(&Bs[cur][(wc * 64 + n * 16 + lr) * 64 + lk]);
#pragma unroll
      for (int m = 0; m < 4; ++m)
#pragma unroll
        for (int n = 0; n < 4; ++n)
          acc[m][n] = __builtin_amdgcn_mfma_f32_16x16x32_bf16(a[m], b[n], acc[m][n], 0, 0, 0);
    }
    asm volatile("" ::: "memory");
    __builtin_amdgcn_s_barrier();  // all waves done reading buf[cur] before overwrite
    cur ^= 1;
  }

  const int row0 = bm * 128 + wr * 64;
  const int col0 = bn * 128 + wc * 64;
#pragma unroll
  for (int m = 0; m < 4; ++m)
#pragma unroll
    for (int n = 0; n < 4; ++n)
#pragma unroll
      for (int j = 0; j < 4; ++j) {
        int r = row0 + m * 16 + (lane >> 4) * 4 + j;
        int c = col0 + n * 16 + (lane & 15);
        float v = acc[m][n][j];
        if (MODE == 0) {
          if (c < 768)
            ((unsigned short*)out0)[(size_t)r * 768 + c] = f2bf(v * 0.125f);  // Q pre-scaled
          else if (c < 1536)
            Kout[(size_t)r * 768 + (c - 768)] = f2bf(v);
          else
            Vt[(size_t)(c - 1536) * M + r] = f2bf(v);
        } else {
          ((float*)out0)[(size_t)r * N + c] = v;
        }
      }
}

// ---------------- attention helpers ----------------
__device__ __forceinline__ void stage_kv(const unsigned short* __restrict__ Kb,
                                         const unsigned short* __restrict__ Vt,
                                         unsigned short* Kbuf, unsigned short* Vbuf,
                                         int h, int st, int wid, int lane) {
  const int cg = lane & 7, rsub = (lane >> 3) & 7;
  const unsigned short* gK = Kb + (size_t)(st * 64) * C_DIM + h * 64;
  const unsigned short* gV = Vt + (size_t)(h * 64) * T_SEQ + st * 64;
#pragma unroll
  for (int c = 0; c < 2; ++c) {
    int seg = wid * 2 + c;
    int row = seg * 8 + rsub;
    GLD16(gK + (size_t)row * C_DIM + (cg ^ rsub) * 8, (char*)Kbuf + seg * 1024);
    GLD16(gV + (size_t)row * T_SEQ + (cg ^ rsub) * 8, (char*)Vbuf + seg * 1024);
  }
}

// partial set id: per head 72 sets (qb>=8 only). offset within head:
__device__ __forceinline__ int part_off(int qb) {
  return (qb < 16) ? (qb - 8) * 2 : (qb < 24) ? 16 + (qb - 16) * 3 : 40 + (qb - 24) * 4;
}
__device__ __forceinline__ unsigned short* part_ptr(char* pA, char* pB, int set) {
  return (set < 768) ? (unsigned short*)(pA + (size_t)set * 16384)
                     : (unsigned short*)(pB + (size_t)(set - 768) * 16384);
}

// ---------------- flash attention (causal, swapped QK^T, s-chunked) ----------------
// grid.x = 80 (qb,ck pairs per head), grid.y = NH
// NOTE: keep global_load_lds staging (no reg-staging: spills, see R4/R5) and
// min-waves 3 (4 caps VGPR at 64 -> spills).
__global__ __launch_bounds__(256, 3)
void attn_fwd(const unsigned short* __restrict__ Qb,
              const unsigned short* __restrict__ Kb,
              const unsigned short* __restrict__ Vt,
              unsigned short* __restrict__ Y,
              char* __restrict__ partA, char* __restrict__ partB,
              float* __restrict__ ml) {
  __shared__ __align__(16) unsigned short Ks[2][64 * 64];
  __shared__ __align__(16) unsigned short Vs[2][64 * 64];  // [d][s]
  __shared__ __align__(16) unsigned short Ps[4][32 * 64];

  const int h = blockIdx.y;
  int qb = 0, ck = 0;
  {
    int idx = blockIdx.x;
    for (int q = 31; q >= 0; --q) {
      int nc = q / 8 + 1;
      if (idx < nc) { qb = q; ck = idx; break; }
      idx -= nc;
    }
  }
  const int nch = qb / 8 + 1;
  const int q0 = qb * 128;
  const int nst_total = q0 / 64 + 2;
  const int st0 = ck * 16;
  const int st1 = (st0 + 16 < nst_total) ? st0 + 16 : nst_total;

  const int tid = threadIdx.x;
  const int wid = tid >> 6, lane = tid & 63;
  const int l15 = lane & 15, g = lane >> 4;
  const int sw = l15 & 7;
  const int qw = q0 + wid * 32;

  bf16x8 qf[2][2];
#pragma unroll
  for (int m = 0; m < 2; ++m)
#pragma unroll
    for (int kk = 0; kk < 2; ++kk)
      qf[m][kk] = *reinterpret_cast<const bf16x8*>(
          &Qb[(size_t)(qw + m * 16 + l15) * C_DIM + h * 64 + kk * 32 + g * 8]);

  f32x4 o[2][4] = {};  // O^T fragments: row=d, col=q
  float mrow[2] = {-1e30f, -1e30f};
  float lsum[2] = {0.f, 0.f};

  stage_kv(Kb, Vt, Ks[0], Vs[0], h, st0, wid, lane);
  int cur = 0;

  for (int st = st0; st < st1; ++st) {
    if (st + 1 < st1) {
      stage_kv(Kb, Vt, Ks[cur ^ 1], Vs[cur ^ 1], h, st + 1, wid, lane);
      asm volatile("s_waitcnt vmcnt(4)" ::: "memory");  // cur tile's 4 loads done
    } else {
      asm volatile("s_waitcnt vmcnt(0)" ::: "memory");
    }
    __builtin_amdgcn_s_barrier();

    const bool active = (st * 64) <= (qw + 31);
    if (active) {
      const unsigned short* K_ = Ks[cur];
      const unsigned short* V_ = Vs[cur];

      // S^T = K @ Q^T
      f32x4 sT[2][4] = {};
      __builtin_amdgcn_s_setprio(1);
#pragma unroll
      for (int kk = 0; kk < 2; ++kk) {
        bf16x8 kf[4];
#pragma unroll
        for (int n = 0; n < 4; ++n)
          kf[n] = *reinterpret_cast<const bf16x8*>(
              &K_[(n * 16 + l15) * 64 + (((kk * 4 + g) ^ sw) * 8)]);
#pragma unroll
        for (int m = 0; m < 2; ++m)
#pragma unroll
          for (int n = 0; n < 4; ++n)
            sT[m][n] = __builtin_amdgcn_mfma_f32_16x16x32_bf16(kf[n], qf[m][kk], sT[m][n], 0, 0, 0);
      }
      __builtin_amdgcn_s_setprio(0);

      unsigned short* Pw = Ps[wid];
#pragma unroll
      for (int m = 0; m < 2; ++m) {
        float vmax = -1e30f;
        if (st * 64 + 63 <= qw + m * 16) {
          // fully unmasked tile for this row-block (wave-uniform branch)
#pragma unroll
          for (int n = 0; n < 4; ++n)
#pragma unroll
            for (int jj = 0; jj < 4; ++jj) vmax = fmaxf(vmax, sT[m][n][jj]);
        } else {
          const int bound = (qw + m * 16 + l15) - st * 64;
#pragma unroll
          for (int n = 0; n < 4; ++n)
#pragma unroll
            for (int jj = 0; jj < 4; ++jj) {
              int sl = n * 16 + g * 4 + jj;
              float v = sT[m][n][jj];
              v = (sl <= bound) ? v : -1e30f;
              sT[m][n][jj] = v;
              vmax = fmaxf(vmax, v);
            }
        }
        vmax = fmaxf(vmax, __shfl_xor(vmax, 16, 64));
        vmax = fmaxf(vmax, __shfl_xor(vmax, 32, 64));
        // defer-rescale with threshold (T13): keep old max while growth <= 8
        const bool defer = (__all(vmax <= mrow[m] + 8.0f) != 0);
        const float mnew = defer ? mrow[m] : fmaxf(mrow[m], vmax);
        float ps = 0.f;
#pragma unroll
        for (int n = 0; n < 4; ++n)
#pragma unroll
          for (int jj = 0; jj < 4; ++jj) {
            float p = __expf(sT[m][n][jj] - mnew);
            sT[m][n][jj] = p;
            ps += p;
          }
        ps += __shfl_xor(ps, 16, 64);
        ps += __shfl_xor(ps, 32, 64);
        if (defer) {
          lsum[m] += ps;
        } else {
          float alpha = __expf(mrow[m] - mnew);
          lsum[m] = lsum[m] * alpha + ps;
          mrow[m] = mnew;
#pragma unroll
          for (int n2 = 0; n2 < 4; ++n2) o[m][n2] *= alpha;
        }
#pragma unroll
        for (int n = 0; n < 4; ++n) {
          uint2 pw;
          pw.x = cvtpk(sT[m][n][0], sT[m][n][1]);
          pw.y = cvtpk(sT[m][n][2], sT[m][n][3]);
          *reinterpret_cast<uint2*>(
              &Pw[(m * 16 + l15) * 64 + (((n * 2 + (g >> 1)) ^ sw) * 8) + (g & 1) * 4]) = pw;
        }
      }
      asm volatile("s_waitcnt lgkmcnt(0)" ::: "memory");

      // O^T += V^T @ P^T
      __builtin_amdgcn_s_setprio(1);
#pragma unroll
      for (int ks = 0; ks < 2; ++ks) {
        bf16x8 vf[4], pf[2];
#pragma unroll
        for (int n2 = 0; n2 < 4; ++n2)
          vf[n2] = *reinterpret_cast<const bf16x8*>(
              &V_[(n2 * 16 + l15) * 64 + (((ks * 4 + g) ^ sw) * 8)]);
#pragma unroll
        for (int m = 0; m < 2; ++m)
          pf[m] = *reinterpret_cast<const bf16x8*>(
              &Pw[(m * 16 + l15) * 64 + (((ks * 4 + g) ^ sw) * 8)]);
#pragma unroll
        for (int m = 0; m < 2; ++m)
#pragma unroll
          for (int n2 = 0; n2 < 4; ++n2)
            o[m][n2] = __builtin_amdgcn_mfma_f32_16x16x32_bf16(vf[n2], pf[m], o[m][n2], 0, 0, 0);
      }
      __builtin_amdgcn_s_setprio(0);
    }
    asm volatile("" ::: "memory");
    __builtin_amdgcn_s_barrier();
    cur ^= 1;
  }

  if (nch == 1) {
#pragma unroll
    for (int m = 0; m < 2; ++m) {
      float inv = 1.0f / lsum[m];
      int qg = qw + m * 16 + l15;
#pragma unroll
      for (int n2 = 0; n2 < 4; ++n2) {
        uint2 yk;
        yk.x = cvtpk(o[m][n2][0] * inv, o[m][n2][1] * inv);
        yk.y = cvtpk(o[m][n2][2] * inv, o[m][n2][3] * inv);
        *reinterpret_cast<uint2*>(&Y[(size_t)qg * C_DIM + h * 64 + n2 * 16 + g * 4]) = yk;
      }
    }
  } else {
    const int set = h * 72 + part_off(qb) + ck;
    unsigned short* po = part_ptr(partA, partB, set);
#pragma unroll
    for (int m = 0; m < 2; ++m) {
      int qL = wid * 32 + m * 16 + l15;
#pragma unroll
      for (int n2 = 0; n2 < 4; ++n2) {
        uint2 pk;
        pk.x = cvtpk(o[m][n2][0], o[m][n2][1]);
        pk.y = cvtpk(o[m][n2][2], o[m][n2][3]);
        *reinterpret_cast<uint2*>(&po[qL * 64 + n2 * 16 + g * 4]) = pk;
      }
      if (g == 0) {
        ml[(size_t)set * 256 + qL * 2] = mrow[m];
        ml[(size_t)set * 256 + qL * 2 + 1] = lsum[m];
      }
    }
  }
}

// ---------------- combine partials ----------------
__global__ __launch_bounds__(256)
void attn_combine(char* __restrict__ partA, char* __restrict__ partB,
                  const float* __restrict__ ml, unsigned short* __restrict__ Y) {
  const int qb = 8 + blockIdx.x;
  const int h = blockIdx.y;
  const int nch = qb / 8 + 1;
  const int set0 = h * 72 + part_off(qb);
  const int t = threadIdx.x;
  const int r = t >> 1, dh = (t & 1) * 32;

  float mi[4], li[4];
  float M = -1e30f;
  for (int i = 0; i < nch; ++i) {
    mi[i] = ml[(size_t)(set0 + i) * 256 + r * 2];
    li[i] = ml[(size_t)(set0 + i) * 256 + r * 2 + 1];
    M = fmaxf(M, mi[i]);
  }
  float L = 0.f;
  float O[32];
#pragma unroll
  for (int d = 0; d < 32; ++d) O[d] = 0.f;
  for (int i = 0; i < nch; ++i) {
    float w = __expf(mi[i] - M);
    L += li[i] * w;
    const unsigned short* po = part_ptr(partA, partB, set0 + i) + r * 64 + dh;
#pragma unroll
    for (int d4 = 0; d4 < 32; d4 += 4) {
      ushort4 v = *reinterpret_cast<const ushort4*>(po + d4);
      O[d4 + 0] += bf2f(v.x) * w;
      O[d4 + 1] += bf2f(v.y) * w;
      O[d4 + 2] += bf2f(v.z) * w;
      O[d4 + 3] += bf2f(v.w) * w;
    }
  }
  float inv = 1.0f / L;
  unsigned short* yp = Y + (size_t)(qb * 128 + r) * C_DIM + h * 64 + dh;
#pragma unroll
  for (int d4 = 0; d4 < 32; d4 += 4) {
    uint2 yk;
    yk.x = cvtpk(O[d4 + 0] * inv, O[d4 + 1] * inv);
    yk.y = cvtpk(O[d4 + 2] * inv, O[d4 + 3] * inv);
    *reinterpret_cast<uint2*>(yp + d4) = yk;
  }
}

// ---------------- launcher ----------------
extern "C" void kernel_launch(void* const* d_in, const int* in_sizes, int n_in,
                              void* d_out, int out_size, void* d_ws, size_t ws_size,
                              hipStream_t stream) {
  const float* x = (const float*)d_in[0];       // [4096][768]
  const float* w_attn = (const float*)d_in[1];  // [768][2304]
  const float* w_proj = (const float*)d_in[2];  // [768][768]
  float* out = (float*)d_out;                   // [4096][768] f32

  char* ws = (char*)d_ws;
  unsigned short* Xb   = (unsigned short*)(ws + 0);          // 6291456 B (dead after QKV -> part spill B)
  unsigned short* WaT  = (unsigned short*)(ws + 6291456);    // 3538944 B (dead after QKV -> ml)
  unsigned short* WpT  = (unsigned short*)(ws + 9830400);    // 1179648 B [768][768]
  unsigned short* Qb   = (unsigned short*)(ws + 11010048);   // 6291456 B [T][768]
  unsigned short* Kb   = (unsigned short*)(ws + 17301504);   // 6291456 B [T][768]
  unsigned short* Vt   = (unsigned short*)(ws + 23592960);   // 6291456 B [768][T]
  unsigned short* Yb   = (unsigned short*)(ws + 29884416);   // 6291456 B [T][768]

  char* partA = (char*)d_out;            // free during attention; overwritten by proj GEMM
  char* partB = (char*)ws;               // Xb region, dead after QKV GEMM
  float* mlp  = (float*)(ws + 6291456);  // WaT region, dead after QKV GEMM

  conv_bf16<<<(T_SEQ * C_DIM / 4 + 255) / 256, 256, 0, stream>>>(x, Xb, T_SEQ * C_DIM);
  transpose_bf16<<<dim3(2304 / 32, 768 / 32), 256, 0, stream>>>(w_attn, WaT, 768, 2304);
  transpose_bf16<<<dim3(768 / 32, 768 / 32), 256, 0, stream>>>(w_proj, WpT, 768, 768);

  gemm_bt<0><<<(T_SEQ / 128) * (2304 / 128), 256, 0, stream>>>(
      Xb, WaT, (void*)Qb, Kb, Vt, T_SEQ, 2304, C_DIM);

  attn_fwd<<<dim3(80, NH), 256, 0, stream>>>(Qb, Kb, Vt, Yb, partA, partB, mlp);
  attn_combine<<<dim3(24, NH), 256, 0, stream>>>(partA, partB, mlp, Yb);

  gemm_bt<1><<<(T_SEQ / 128) * (C_DIM / 128), 256, 0, stream>>>(
      Yb, WpT, (void*)out, nullptr, nullptr, T_SEQ, C_DIM, C_DIM);
}

// Round 8
// 151.512 us; speedup vs baseline: 1.0651x; 1.0651x over previous
//
#include <hip/hip_runtime.h>

// Causal self-attention: B=1, T=4096, C=768, H=12, hd=64
// f32 in/out, bf16 MFMA compute internally. Flash-decoding s-split.
// R8: GEMMs reverted to R6 structure (R7 dbuf 64KB LDS -> 2 blocks/CU cost
// ~15us; latency-bound small-K GEMMs need the TLP). attn: 8-wave blocks
// (QBLK=256) amortize K/V LDS over 8 waves -> 4 waves/SIMD, 480 blocks all
// co-resident.

typedef short bf16x8 __attribute__((ext_vector_type(8)));
typedef float f32x4 __attribute__((ext_vector_type(4)));

#define T_SEQ 4096
#define C_DIM 768
#define NH 12
#define HD 64

__device__ __forceinline__ unsigned short f2bf(float f) {
  union { float f; unsigned u; } v; v.f = f;
  unsigned r = v.u + 0x7FFFu + ((v.u >> 16) & 1u);
  return (unsigned short)(r >> 16);
}
__device__ __forceinline__ float bf2f(unsigned short u) {
  union { unsigned u; float f; } v; v.u = ((unsigned)u) << 16;
  return v.f;
}
__device__ __forceinline__ unsigned cvtpk(float a, float b) {
  unsigned r;
  asm("v_cvt_pk_bf16_f32 %0, %1, %2" : "=v"(r) : "v"(a), "v"(b));
  return r;
}

#define GLD16(g, l) __builtin_amdgcn_global_load_lds( \
    (const __attribute__((address_space(1))) void*)(g), \
    (__attribute__((address_space(3))) void*)(l), 16, 0, 0)

// ---------------- f32 -> bf16 convert (vectorized) ----------------
__global__ void conv_bf16(const float* __restrict__ in, unsigned short* __restrict__ out, int n) {
  int i = (blockIdx.x * blockDim.x + threadIdx.x) * 4;
  if (i + 3 < n) {
    float4 v = *reinterpret_cast<const float4*>(in + i);
    ushort4 o;
    o.x = f2bf(v.x); o.y = f2bf(v.y); o.z = f2bf(v.z); o.w = f2bf(v.w);
    *reinterpret_cast<ushort4*>(out + i) = o;
  }
}

// ---------------- transpose f32 [R][Cc] -> bf16 [Cc][R] ----------------
__global__ void transpose_bf16(const float* __restrict__ in, unsigned short* __restrict__ out,
                               int R, int Cc) {
  __shared__ float tile[32][33];
  int bx = blockIdx.x * 32;
  int by = blockIdx.y * 32;
  int tx = threadIdx.x & 31, ty = threadIdx.x >> 5;
#pragma unroll
  for (int i = 0; i < 32; i += 8)
    tile[ty + i][tx] = in[(size_t)(by + ty + i) * Cc + bx + tx];
  __syncthreads();
#pragma unroll
  for (int i = 0; i < 32; i += 8)
    out[(size_t)(bx + ty + i) * R + by + tx] = f2bf(tile[tx][ty + i]);
}

// ---------------- BT-GEMM: A[M][K] bf16 @ Bt[N][K] bf16 (R6 structure) ----------------
template <int MODE>
__global__ __launch_bounds__(256, 2)
void gemm_bt(const unsigned short* __restrict__ A,
             const unsigned short* __restrict__ Bt,
             void* __restrict__ out0,
             unsigned short* __restrict__ Kout,
             unsigned short* __restrict__ Vt,
             int M, int N, int K) {
  __shared__ __align__(16) unsigned short As[128 * 64];
  __shared__ __align__(16) unsigned short Bs[128 * 64];
  const int bm = blockIdx.x, bn = blockIdx.y;
  const int tid = threadIdx.x;
  const int wid = tid >> 6, lane = tid & 63;
  const int wr = wid >> 1, wc = wid & 1;
  const int lr = lane & 15;
  const int lk8 = (lane >> 4) * 8;

  f32x4 acc[4][4] = {};

  const int nk = K / 64;
  for (int kt = 0; kt < nk; ++kt) {
    __syncthreads();
    {
      const unsigned short* gA = A + (size_t)(bm * 128) * K + kt * 64;
      const unsigned short* gB = Bt + (size_t)(bn * 128) * K + kt * 64;
      int rsub = lane >> 3, csub = (lane & 7) * 8;
#pragma unroll
      for (int c = 0; c < 4; ++c) {
        int seg = wid * 4 + c;
        int row = seg * 8 + rsub;
        GLD16(gA + (size_t)row * K + csub, (char*)As + seg * 1024);
      }
#pragma unroll
      for (int c = 0; c < 4; ++c) {
        int seg = wid * 4 + c;
        int row = seg * 8 + rsub;
        GLD16(gB + (size_t)row * K + csub, (char*)Bs + seg * 1024);
      }
    }
    __syncthreads();
#pragma unroll
    for (int kk = 0; kk < 2; ++kk) {
      bf16x8 a[4], b[4];
      int lk = kk * 32 + lk8;
#pragma unroll
      for (int m = 0; m < 4; ++m)
        a[m] = *reinterpret_cast<const bf16x8*>(&As[(wr * 64 + m * 16 + lr) * 64 + lk]);
#pragma unroll
      for (int n = 0; n < 4; ++n)
        b[n] = *reinterpret_cast<const bf16x8*>(&Bs[(wc * 64 + n * 16 + lr) * 64 + lk]);
#pragma unroll
      for (int m = 0; m < 4; ++m)
#pragma unroll
        for (int n = 0; n < 4; ++n)
          acc[m][n] = __builtin_amdgcn_mfma_f32_16x16x32_bf16(a[m], b[n], acc[m][n], 0, 0, 0);
    }
  }

  const int row0 = bm * 128 + wr * 64;
  const int col0 = bn * 128 + wc * 64;
#pragma unroll
  for (int m = 0; m < 4; ++m)
#pragma unroll
    for (int n = 0; n < 4; ++n)
#pragma unroll
      for (int j = 0; j < 4; ++j) {
        int r = row0 + m * 16 + (lane >> 4) * 4 + j;
        int c = col0 + n * 16 + (lane & 15);
        float v = acc[m][n][j];
        if (MODE == 0) {
          if (c < 768)
            ((unsigned short*)out0)[(size_t)r * 768 + c] = f2bf(v * 0.125f);  // Q pre-scaled
          else if (c < 1536)
            Kout[(size_t)r * 768 + (c - 768)] = f2bf(v);
          else
            Vt[(size_t)(c - 1536) * M + r] = f2bf(v);
        } else {
          ((float*)out0)[(size_t)r * N + c] = v;
        }
      }
}

// ---------------- attention helpers ----------------
// 8-wave staging: each wave stages 1 seg (8 rows) of K and 1 of V (2 loads/wave)
__device__ __forceinline__ void stage_kv(const unsigned short* __restrict__ Kb,
                                         const unsigned short* __restrict__ Vt,
                                         unsigned short* Kbuf, unsigned short* Vbuf,
                                         int h, int st, int wid, int lane) {
  const int cg = lane & 7, rsub = (lane >> 3) & 7;
  const int row = wid * 8 + rsub;
  const unsigned short* gK = Kb + (size_t)(st * 64) * C_DIM + h * 64;
  const unsigned short* gV = Vt + (size_t)(h * 64) * T_SEQ + st * 64;
  GLD16(gK + (size_t)row * C_DIM + (cg ^ rsub) * 8, (char*)Kbuf + wid * 1024);
  GLD16(gV + (size_t)row * T_SEQ + (cg ^ rsub) * 8, (char*)Vbuf + wid * 1024);
}

// chunks per qb (QBLK=256): tiles = 4qb+4, chunk = 16 tiles
__device__ __forceinline__ int nchunks(int q) {
  return (q < 4) ? 1 : (q < 8) ? 2 : (q < 12) ? 3 : 4;
}
// partial set offset within head (qb>=4 only): 36 sets/head
__device__ __forceinline__ int part_off(int qb) {
  return (qb < 8) ? (qb - 4) * 2 : (qb < 12) ? 8 + (qb - 8) * 3 : 20 + (qb - 12) * 4;
}
// 432 sets x 32KB: first 384 in d_out (12MB), rest in Xb region
__device__ __forceinline__ unsigned short* part_ptr(char* pA, char* pB, int set) {
  return (set < 384) ? (unsigned short*)(pA + (size_t)set * 32768)
                     : (unsigned short*)(pB + (size_t)(set - 384) * 32768);
}

// ---------------- flash attention (causal, swapped QK^T, s-chunked) ----------------
// grid = (40, NH), 512 threads (8 waves x 32 q-rows = 256 q/block)
// NOTE: global_load_lds staging (reg-staging spills: R4/R5); min-waves 3.
__global__ __launch_bounds__(512, 3)
void attn_fwd(const unsigned short* __restrict__ Qb,
              const unsigned short* __restrict__ Kb,
              const unsigned short* __restrict__ Vt,
              unsigned short* __restrict__ Y,
              char* __restrict__ partA, char* __restrict__ partB,
              float* __restrict__ ml) {
  __shared__ __align__(16) unsigned short Ks[2][64 * 64];
  __shared__ __align__(16) unsigned short Vs[2][64 * 64];  // [d][s]
  __shared__ __align__(16) unsigned short Ps[8][32 * 64];

  const int h = blockIdx.y;
  int qb = 0, ck = 0;
  {
    int idx = blockIdx.x;
    for (int q = 15; q >= 0; --q) {
      int nc = nchunks(q);
      if (idx < nc) { qb = q; ck = idx; break; }
      idx -= nc;
    }
  }
  const int nch = nchunks(qb);
  const int q0 = qb * 256;
  const int nst_total = 4 * qb + 4;
  const int st0 = ck * 16;
  const int st1 = (st0 + 16 < nst_total) ? st0 + 16 : nst_total;

  const int tid = threadIdx.x;
  const int wid = tid >> 6, lane = tid & 63;
  const int l15 = lane & 15, g = lane >> 4;
  const int sw = l15 & 7;
  const int qw = q0 + wid * 32;

  bf16x8 qf[2][2];
#pragma unroll
  for (int m = 0; m < 2; ++m)
#pragma unroll
    for (int kk = 0; kk < 2; ++kk)
      qf[m][kk] = *reinterpret_cast<const bf16x8*>(
          &Qb[(size_t)(qw + m * 16 + l15) * C_DIM + h * 64 + kk * 32 + g * 8]);

  f32x4 o[2][4] = {};  // O^T fragments: row=d, col=q
  float mrow[2] = {-1e30f, -1e30f};
  float lsum[2] = {0.f, 0.f};

  stage_kv(Kb, Vt, Ks[0], Vs[0], h, st0, wid, lane);
  int cur = 0;

  for (int st = st0; st < st1; ++st) {
    if (st + 1 < st1) {
      stage_kv(Kb, Vt, Ks[cur ^ 1], Vs[cur ^ 1], h, st + 1, wid, lane);
      asm volatile("s_waitcnt vmcnt(2)" ::: "memory");  // cur tile's 2 loads done
    } else {
      asm volatile("s_waitcnt vmcnt(0)" ::: "memory");
    }
    __builtin_amdgcn_s_barrier();

    const bool active = (st * 64) <= (qw + 31);
    if (active) {
      const unsigned short* K_ = Ks[cur];
      const unsigned short* V_ = Vs[cur];

      // S^T = K @ Q^T
      f32x4 sT[2][4] = {};
      __builtin_amdgcn_s_setprio(1);
#pragma unroll
      for (int kk = 0; kk < 2; ++kk) {
        bf16x8 kf[4];
#pragma unroll
        for (int n = 0; n < 4; ++n)
          kf[n] = *reinterpret_cast<const bf16x8*>(
              &K_[(n * 16 + l15) * 64 + (((kk * 4 + g) ^ sw) * 8)]);
#pragma unroll
        for (int m = 0; m < 2; ++m)
#pragma unroll
          for (int n = 0; n < 4; ++n)
            sT[m][n] = __builtin_amdgcn_mfma_f32_16x16x32_bf16(kf[n], qf[m][kk], sT[m][n], 0, 0, 0);
      }
      __builtin_amdgcn_s_setprio(0);

      unsigned short* Pw = Ps[wid];
#pragma unroll
      for (int m = 0; m < 2; ++m) {
        float vmax = -1e30f;
        if (st * 64 + 63 <= qw + m * 16) {
          // fully unmasked tile for this row-block (wave-uniform branch)
#pragma unroll
          for (int n = 0; n < 4; ++n)
#pragma unroll
            for (int jj = 0; jj < 4; ++jj) vmax = fmaxf(vmax, sT[m][n][jj]);
        } else {
          const int bound = (qw + m * 16 + l15) - st * 64;
#pragma unroll
          for (int n = 0; n < 4; ++n)
#pragma unroll
            for (int jj = 0; jj < 4; ++jj) {
              int sl = n * 16 + g * 4 + jj;
              float v = sT[m][n][jj];
              v = (sl <= bound) ? v : -1e30f;
              sT[m][n][jj] = v;
              vmax = fmaxf(vmax, v);
            }
        }
        vmax = fmaxf(vmax, __shfl_xor(vmax, 16, 64));
        vmax = fmaxf(vmax, __shfl_xor(vmax, 32, 64));
        // defer-rescale with threshold (T13): keep old max while growth <= 8
        const bool defer = (__all(vmax <= mrow[m] + 8.0f) != 0);
        const float mnew = defer ? mrow[m] : fmaxf(mrow[m], vmax);
        float ps = 0.f;
#pragma unroll
        for (int n = 0; n < 4; ++n)
#pragma unroll
          for (int jj = 0; jj < 4; ++jj) {
            float p = __expf(sT[m][n][jj] - mnew);
            sT[m][n][jj] = p;
            ps += p;
          }
        ps += __shfl_xor(ps, 16, 64);
        ps += __shfl_xor(ps, 32, 64);
        if (defer) {
          lsum[m] += ps;
        } else {
          float alpha = __expf(mrow[m] - mnew);
          lsum[m] = lsum[m] * alpha + ps;
          mrow[m] = mnew;
#pragma unroll
          for (int n2 = 0; n2 < 4; ++n2) o[m][n2] *= alpha;
        }
#pragma unroll
        for (int n = 0; n < 4; ++n) {
          uint2 pw;
          pw.x = cvtpk(sT[m][n][0], sT[m][n][1]);
          pw.y = cvtpk(sT[m][n][2], sT[m][n][3]);
          *reinterpret_cast<uint2*>(
              &Pw[(m * 16 + l15) * 64 + (((n * 2 + (g >> 1)) ^ sw) * 8) + (g & 1) * 4]) = pw;
        }
      }
      asm volatile("s_waitcnt lgkmcnt(0)" ::: "memory");

      // O^T += V^T @ P^T
      __builtin_amdgcn_s_setprio(1);
#pragma unroll
      for (int ks = 0; ks < 2; ++ks) {
        bf16x8 vf[4], pf[2];
#pragma unroll
        for (int n2 = 0; n2 < 4; ++n2)
          vf[n2] = *reinterpret_cast<const bf16x8*>(
              &V_[(n2 * 16 + l15) * 64 + (((ks * 4 + g) ^ sw) * 8)]);
#pragma unroll
        for (int m = 0; m < 2; ++m)
          pf[m] = *reinterpret_cast<const bf16x8*>(
              &Pw[(m * 16 + l15) * 64 + (((ks * 4 + g) ^ sw) * 8)]);
#pragma unroll
        for (int m = 0; m < 2; ++m)
#pragma unroll
          for (int n2 = 0; n2 < 4; ++n2)
            o[m][n2] = __builtin_amdgcn_mfma_f32_16x16x32_bf16(vf[n2], pf[m], o[m][n2], 0, 0, 0);
      }
      __builtin_amdgcn_s_setprio(0);
    }
    asm volatile("" ::: "memory");
    __builtin_amdgcn_s_barrier();
    cur ^= 1;
  }

  if (nch == 1) {
#pragma unroll
    for (int m = 0; m < 2; ++m) {
      float inv = 1.0f / lsum[m];
      int qg = qw + m * 16 + l15;
#pragma unroll
      for (int n2 = 0; n2 < 4; ++n2) {
        uint2 yk;
        yk.x = cvtpk(o[m][n2][0] * inv, o[m][n2][1] * inv);
        yk.y = cvtpk(o[m][n2][2] * inv, o[m][n2][3] * inv);
        *reinterpret_cast<uint2*>(&Y[(size_t)qg * C_DIM + h * 64 + n2 * 16 + g * 4]) = yk;
      }
    }
  } else {
    const int set = h * 36 + part_off(qb) + ck;
    unsigned short* po = part_ptr(partA, partB, set);
#pragma unroll
    for (int m = 0; m < 2; ++m) {
      int qL = wid * 32 + m * 16 + l15;  // 0..255
#pragma unroll
      for (int n2 = 0; n2 < 4; ++n2) {
        uint2 pk;
        pk.x = cvtpk(o[m][n2][0], o[m][n2][1]);
        pk.y = cvtpk(o[m][n2][2], o[m][n2][3]);
        *reinterpret_cast<uint2*>(&po[qL * 64 + n2 * 16 + g * 4]) = pk;
      }
      if (g == 0) {
        ml[(size_t)set * 512 + qL * 2] = mrow[m];
        ml[(size_t)set * 512 + qL * 2 + 1] = lsum[m];
      }
    }
  }
}

// ---------------- combine partials ----------------
// grid (12, NH), 512 threads: qb = 4 + bx, 256 rows x 2 d-halves
__global__ __launch_bounds__(512)
void attn_combine(char* __restrict__ partA, char* __restrict__ partB,
                  const float* __restrict__ ml, unsigned short* __restrict__ Y) {
  const int qb = 4 + blockIdx.x;
  const int h = blockIdx.y;
  const int nch = nchunks(qb);
  const int set0 = h * 36 + part_off(qb);
  const int t = threadIdx.x;
  const int r = t >> 1, dh = (t & 1) * 32;

  float mi[4], li[4];
  float M = -1e30f;
  for (int i = 0; i < nch; ++i) {
    mi[i] = ml[(size_t)(set0 + i) * 512 + r * 2];
    li[i] = ml[(size_t)(set0 + i) * 512 + r * 2 + 1];
    M = fmaxf(M, mi[i]);
  }
  float L = 0.f;
  float O[32];
#pragma unroll
  for (int d = 0; d < 32; ++d) O[d] = 0.f;
  for (int i = 0; i < nch; ++i) {
    float w = __expf(mi[i] - M);
    L += li[i] * w;
    const unsigned short* po = part_ptr(partA, partB, set0 + i) + r * 64 + dh;
#pragma unroll
    for (int d4 = 0; d4 < 32; d4 += 4) {
      ushort4 v = *reinterpret_cast<const ushort4*>(po + d4);
      O[d4 + 0] += bf2f(v.x) * w;
      O[d4 + 1] += bf2f(v.y) * w;
      O[d4 + 2] += bf2f(v.z) * w;
      O[d4 + 3] += bf2f(v.w) * w;
    }
  }
  float inv = 1.0f / L;
  unsigned short* yp = Y + (size_t)(qb * 256 + r) * C_DIM + h * 64 + dh;
#pragma unroll
  for (int d4 = 0; d4 < 32; d4 += 4) {
    uint2 yk;
    yk.x = cvtpk(O[d4 + 0] * inv, O[d4 + 1] * inv);
    yk.y = cvtpk(O[d4 + 2] * inv, O[d4 + 3] * inv);
    *reinterpret_cast<uint2*>(yp + d4) = yk;
  }
}

// ---------------- launcher ----------------
extern "C" void kernel_launch(void* const* d_in, const int* in_sizes, int n_in,
                              void* d_out, int out_size, void* d_ws, size_t ws_size,
                              hipStream_t stream) {
  const float* x = (const float*)d_in[0];       // [4096][768]
  const float* w_attn = (const float*)d_in[1];  // [768][2304]
  const float* w_proj = (const float*)d_in[2];  // [768][768]
  float* out = (float*)d_out;                   // [4096][768] f32

  char* ws = (char*)d_ws;
  unsigned short* Xb   = (unsigned short*)(ws + 0);          // 6291456 B (dead after QKV -> part spill B)
  unsigned short* WaT  = (unsigned short*)(ws + 6291456);    // 3538944 B (dead after QKV -> ml)
  unsigned short* WpT  = (unsigned short*)(ws + 9830400);    // 1179648 B [768][768]
  unsigned short* Qb   = (unsigned short*)(ws + 11010048);   // 6291456 B [T][768]
  unsigned short* Kb   = (unsigned short*)(ws + 17301504);   // 6291456 B [T][768]
  unsigned short* Vt   = (unsigned short*)(ws + 23592960);   // 6291456 B [768][T]
  unsigned short* Yb   = (unsigned short*)(ws + 29884416);   // 6291456 B [T][768]

  char* partA = (char*)d_out;            // free during attention; overwritten by proj GEMM
  char* partB = (char*)ws;               // Xb region, dead after QKV GEMM
  float* mlp  = (float*)(ws + 6291456);  // WaT region, dead after QKV GEMM

  conv_bf16<<<(T_SEQ * C_DIM / 4 + 255) / 256, 256, 0, stream>>>(x, Xb, T_SEQ * C_DIM);
  transpose_bf16<<<dim3(2304 / 32, 768 / 32), 256, 0, stream>>>(w_attn, WaT, 768, 2304);
  transpose_bf16<<<dim3(768 / 32, 768 / 32), 256, 0, stream>>>(w_proj, WpT, 768, 768);

  gemm_bt<0><<<dim3(T_SEQ / 128, 2304 / 128), 256, 0, stream>>>(
      Xb, WaT, (void*)Qb, Kb, Vt, T_SEQ, 2304, C_DIM);

  attn_fwd<<<dim3(40, NH), 512, 0, stream>>>(Qb, Kb, Vt, Yb, partA, partB, mlp);
  attn_combine<<<dim3(12, NH), 512, 0, stream>>>(partA, partB, mlp, Yb);

  gemm_bt<1><<<dim3(T_SEQ / 128, C_DIM / 128), 256, 0, stream>>>(
      Yb, WpT, (void*)out, nullptr, nullptr, T_SEQ, C_DIM, C_DIM);
}

// Round 9
// 148.939 us; speedup vs baseline: 1.0835x; 1.0173x over previous
//
#include <hip/hip_runtime.h>

// Causal self-attention: B=1, T=4096, C=768, H=12, hd=64
// f32 in/out, bf16 MFMA compute internally. Flash-decoding s-split.
// R9: attn = R6 structure (960 blocks/4 waves) + P-split PV -> Ps 16->8KB,
// LDS 48->40KB -> 4 blocks/CU. GEMM tile 128x64 -> 2x blocks (TLP was the
// GEMM limit, not prefetch: R7 lesson).

typedef short bf16x8 __attribute__((ext_vector_type(8)));
typedef float f32x4 __attribute__((ext_vector_type(4)));

#define T_SEQ 4096
#define C_DIM 768
#define NH 12
#define HD 64

__device__ __forceinline__ unsigned short f2bf(float f) {
  union { float f; unsigned u; } v; v.f = f;
  unsigned r = v.u + 0x7FFFu + ((v.u >> 16) & 1u);
  return (unsigned short)(r >> 16);
}
__device__ __forceinline__ float bf2f(unsigned short u) {
  union { unsigned u; float f; } v; v.u = ((unsigned)u) << 16;
  return v.f;
}
__device__ __forceinline__ unsigned cvtpk(float a, float b) {
  unsigned r;
  asm("v_cvt_pk_bf16_f32 %0, %1, %2" : "=v"(r) : "v"(a), "v"(b));
  return r;
}

#define GLD16(g, l) __builtin_amdgcn_global_load_lds( \
    (const __attribute__((address_space(1))) void*)(g), \
    (__attribute__((address_space(3))) void*)(l), 16, 0, 0)

// ---------------- f32 -> bf16 convert (vectorized) ----------------
__global__ void conv_bf16(const float* __restrict__ in, unsigned short* __restrict__ out, int n) {
  int i = (blockIdx.x * blockDim.x + threadIdx.x) * 4;
  if (i + 3 < n) {
    float4 v = *reinterpret_cast<const float4*>(in + i);
    ushort4 o;
    o.x = f2bf(v.x); o.y = f2bf(v.y); o.z = f2bf(v.z); o.w = f2bf(v.w);
    *reinterpret_cast<ushort4*>(out + i) = o;
  }
}

// ---------------- transpose f32 [R][Cc] -> bf16 [Cc][R] ----------------
__global__ void transpose_bf16(const float* __restrict__ in, unsigned short* __restrict__ out,
                               int R, int Cc) {
  __shared__ float tile[32][33];
  int bx = blockIdx.x * 32;
  int by = blockIdx.y * 32;
  int tx = threadIdx.x & 31, ty = threadIdx.x >> 5;
#pragma unroll
  for (int i = 0; i < 32; i += 8)
    tile[ty + i][tx] = in[(size_t)(by + ty + i) * Cc + bx + tx];
  __syncthreads();
#pragma unroll
  for (int i = 0; i < 32; i += 8)
    out[(size_t)(bx + ty + i) * R + by + tx] = f2bf(tile[tx][ty + i]);
}

// ---------------- BT-GEMM: A[M][K] bf16 @ Bt[N][K] bf16 ----------------
// Tile 128x64 (R9: more blocks -> TLP; LDS 24KB -> 6 blocks/CU).
template <int MODE>
__global__ __launch_bounds__(256, 2)
void gemm_bt(const unsigned short* __restrict__ A,
             const unsigned short* __restrict__ Bt,
             void* __restrict__ out0,
             unsigned short* __restrict__ Kout,
             unsigned short* __restrict__ Vt,
             int M, int N, int K) {
  __shared__ __align__(16) unsigned short As[128 * 64];
  __shared__ __align__(16) unsigned short Bs[64 * 64];
  const int bm = blockIdx.x, bn = blockIdx.y;
  const int tid = threadIdx.x;
  const int wid = tid >> 6, lane = tid & 63;
  const int wr = wid >> 1, wc = wid & 1;
  const int lr = lane & 15;
  const int lk8 = (lane >> 4) * 8;
  const int rsub = lane >> 3, csub = (lane & 7) * 8;

  f32x4 acc[4][2] = {};

  const int nk = K / 64;
  for (int kt = 0; kt < nk; ++kt) {
    __syncthreads();
    {
      const unsigned short* gA = A + (size_t)(bm * 128) * K + kt * 64;
      const unsigned short* gB = Bt + (size_t)(bn * 64) * K + kt * 64;
#pragma unroll
      for (int c = 0; c < 4; ++c) {
        int seg = wid * 4 + c;            // A: 16 segs of 1KB
        int row = seg * 8 + rsub;
        GLD16(gA + (size_t)row * K + csub, (char*)As + seg * 1024);
      }
#pragma unroll
      for (int c = 0; c < 2; ++c) {
        int seg = wid * 2 + c;            // B: 8 segs of 1KB
        int row = seg * 8 + rsub;
        GLD16(gB + (size_t)row * K + csub, (char*)Bs + seg * 1024);
      }
    }
    __syncthreads();
#pragma unroll
    for (int kk = 0; kk < 2; ++kk) {
      bf16x8 a[4], b[2];
      int lk = kk * 32 + lk8;
#pragma unroll
      for (int m = 0; m < 4; ++m)
        a[m] = *reinterpret_cast<const bf16x8*>(&As[(wr * 64 + m * 16 + lr) * 64 + lk]);
#pragma unroll
      for (int n = 0; n < 2; ++n)
        b[n] = *reinterpret_cast<const bf16x8*>(&Bs[(wc * 32 + n * 16 + lr) * 64 + lk]);
#pragma unroll
      for (int m = 0; m < 4; ++m)
#pragma unroll
        for (int n = 0; n < 2; ++n)
          acc[m][n] = __builtin_amdgcn_mfma_f32_16x16x32_bf16(a[m], b[n], acc[m][n], 0, 0, 0);
    }
  }

  const int row0 = bm * 128 + wr * 64;
  const int col0 = bn * 64 + wc * 32;
#pragma unroll
  for (int m = 0; m < 4; ++m)
#pragma unroll
    for (int n = 0; n < 2; ++n)
#pragma unroll
      for (int j = 0; j < 4; ++j) {
        int r = row0 + m * 16 + (lane >> 4) * 4 + j;
        int c = col0 + n * 16 + (lane & 15);
        float v = acc[m][n][j];
        if (MODE == 0) {
          if (c < 768)
            ((unsigned short*)out0)[(size_t)r * 768 + c] = f2bf(v * 0.125f);  // Q pre-scaled
          else if (c < 1536)
            Kout[(size_t)r * 768 + (c - 768)] = f2bf(v);
          else
            Vt[(size_t)(c - 1536) * M + r] = f2bf(v);
        } else {
          ((float*)out0)[(size_t)r * N + c] = v;
        }
      }
}

// ---------------- attention helpers ----------------
__device__ __forceinline__ void stage_kv(const unsigned short* __restrict__ Kb,
                                         const unsigned short* __restrict__ Vt,
                                         unsigned short* Kbuf, unsigned short* Vbuf,
                                         int h, int st, int wid, int lane) {
  const int cg = lane & 7, rsub = (lane >> 3) & 7;
  const unsigned short* gK = Kb + (size_t)(st * 64) * C_DIM + h * 64;
  const unsigned short* gV = Vt + (size_t)(h * 64) * T_SEQ + st * 64;
#pragma unroll
  for (int c = 0; c < 2; ++c) {
    int seg = wid * 2 + c;
    int row = seg * 8 + rsub;
    GLD16(gK + (size_t)row * C_DIM + (cg ^ rsub) * 8, (char*)Kbuf + seg * 1024);
    GLD16(gV + (size_t)row * T_SEQ + (cg ^ rsub) * 8, (char*)Vbuf + seg * 1024);
  }
}

// partial set id: per head 72 sets (qb>=8 only). offset within head:
__device__ __forceinline__ int part_off(int qb) {
  return (qb < 16) ? (qb - 8) * 2 : (qb < 24) ? 16 + (qb - 16) * 3 : 40 + (qb - 24) * 4;
}
__device__ __forceinline__ unsigned short* part_ptr(char* pA, char* pB, int set) {
  return (set < 768) ? (unsigned short*)(pA + (size_t)set * 16384)
                     : (unsigned short*)(pB + (size_t)(set - 768) * 16384);
}

// ---------------- flash attention (causal, swapped QK^T, s-chunked) ----------------
// grid.x = 80 (qb,ck pairs per head), grid.y = NH
// LDS 40KB (Ps split per m-half) -> 4 blocks/CU. global_load_lds staging
// (reg-staging spills: R4/R5); min-waves 3 (4 caps VGPR at 64 -> spills).
__global__ __launch_bounds__(256, 3)
void attn_fwd(const unsigned short* __restrict__ Qb,
              const unsigned short* __restrict__ Kb,
              const unsigned short* __restrict__ Vt,
              unsigned short* __restrict__ Y,
              char* __restrict__ partA, char* __restrict__ partB,
              float* __restrict__ ml) {
  __shared__ __align__(16) unsigned short Ks[2][64 * 64];
  __shared__ __align__(16) unsigned short Vs[2][64 * 64];  // [d][s]
  __shared__ __align__(16) unsigned short Ps[4][16 * 64];  // per-wave P m-half

  const int h = blockIdx.y;
  int qb = 0, ck = 0;
  {
    int idx = blockIdx.x;
    for (int q = 31; q >= 0; --q) {
      int nc = q / 8 + 1;
      if (idx < nc) { qb = q; ck = idx; break; }
      idx -= nc;
    }
  }
  const int nch = qb / 8 + 1;
  const int q0 = qb * 128;
  const int nst_total = q0 / 64 + 2;
  const int st0 = ck * 16;
  const int st1 = (st0 + 16 < nst_total) ? st0 + 16 : nst_total;

  const int tid = threadIdx.x;
  const int wid = tid >> 6, lane = tid & 63;
  const int l15 = lane & 15, g = lane >> 4;
  const int sw = l15 & 7;
  const int qw = q0 + wid * 32;

  bf16x8 qf[2][2];
#pragma unroll
  for (int m = 0; m < 2; ++m)
#pragma unroll
    for (int kk = 0; kk < 2; ++kk)
      qf[m][kk] = *reinterpret_cast<const bf16x8*>(
          &Qb[(size_t)(qw + m * 16 + l15) * C_DIM + h * 64 + kk * 32 + g * 8]);

  f32x4 o[2][4] = {};  // O^T fragments: row=d, col=q
  float mrow[2] = {-1e30f, -1e30f};
  float lsum[2] = {0.f, 0.f};

  stage_kv(Kb, Vt, Ks[0], Vs[0], h, st0, wid, lane);
  int cur = 0;

  for (int st = st0; st < st1; ++st) {
    if (st + 1 < st1) {
      stage_kv(Kb, Vt, Ks[cur ^ 1], Vs[cur ^ 1], h, st + 1, wid, lane);
      asm volatile("s_waitcnt vmcnt(4)" ::: "memory");  // cur tile's 4 loads done
    } else {
      asm volatile("s_waitcnt vmcnt(0)" ::: "memory");
    }
    __builtin_amdgcn_s_barrier();

    const bool active = (st * 64) <= (qw + 31);
    if (active) {
      const unsigned short* K_ = Ks[cur];
      const unsigned short* V_ = Vs[cur];

      // S^T = K @ Q^T
      f32x4 sT[2][4] = {};
      __builtin_amdgcn_s_setprio(1);
#pragma unroll
      for (int kk = 0; kk < 2; ++kk) {
        bf16x8 kf[4];
#pragma unroll
        for (int n = 0; n < 4; ++n)
          kf[n] = *reinterpret_cast<const bf16x8*>(
              &K_[(n * 16 + l15) * 64 + (((kk * 4 + g) ^ sw) * 8)]);
#pragma unroll
        for (int m = 0; m < 2; ++m)
#pragma unroll
          for (int n = 0; n < 4; ++n)
            sT[m][n] = __builtin_amdgcn_mfma_f32_16x16x32_bf16(kf[n], qf[m][kk], sT[m][n], 0, 0, 0);
      }
      __builtin_amdgcn_s_setprio(0);

      unsigned short* Pw = Ps[wid];
#pragma unroll
      for (int m = 0; m < 2; ++m) {
        float vmax = -1e30f;
        if (st * 64 + 63 <= qw + m * 16) {
          // fully unmasked tile for this row-block (wave-uniform branch)
#pragma unroll
          for (int n = 0; n < 4; ++n)
#pragma unroll
            for (int jj = 0; jj < 4; ++jj) vmax = fmaxf(vmax, sT[m][n][jj]);
        } else {
          const int bound = (qw + m * 16 + l15) - st * 64;
#pragma unroll
          for (int n = 0; n < 4; ++n)
#pragma unroll
            for (int jj = 0; jj < 4; ++jj) {
              int sl = n * 16 + g * 4 + jj;
              float v = sT[m][n][jj];
              v = (sl <= bound) ? v : -1e30f;
              sT[m][n][jj] = v;
              vmax = fmaxf(vmax, v);
            }
        }
        vmax = fmaxf(vmax, __shfl_xor(vmax, 16, 64));
        vmax = fmaxf(vmax, __shfl_xor(vmax, 32, 64));
        // defer-rescale with threshold (T13): keep old max while growth <= 8
        const bool defer = (__all(vmax <= mrow[m] + 8.0f) != 0);
        const float mnew = defer ? mrow[m] : fmaxf(mrow[m], vmax);
        float ps = 0.f;
#pragma unroll
        for (int n = 0; n < 4; ++n)
#pragma unroll
          for (int jj = 0; jj < 4; ++jj) {
            float p = __expf(sT[m][n][jj] - mnew);
            sT[m][n][jj] = p;
            ps += p;
          }
        ps += __shfl_xor(ps, 16, 64);
        ps += __shfl_xor(ps, 32, 64);
        if (defer) {
          lsum[m] += ps;
        } else {
          float alpha = __expf(mrow[m] - mnew);
          lsum[m] = lsum[m] * alpha + ps;
          mrow[m] = mnew;
#pragma unroll
          for (int n2 = 0; n2 < 4; ++n2) o[m][n2] *= alpha;
        }
        // store this m-half's P (16 rows x 64 s) into per-wave 2KB slice
#pragma unroll
        for (int n = 0; n < 4; ++n) {
          uint2 pw;
          pw.x = cvtpk(sT[m][n][0], sT[m][n][1]);
          pw.y = cvtpk(sT[m][n][2], sT[m][n][3]);
          *reinterpret_cast<uint2*>(
              &Pw[l15 * 64 + (((n * 2 + (g >> 1)) ^ sw) * 8) + (g & 1) * 4]) = pw;
        }
        asm volatile("s_waitcnt lgkmcnt(0)" ::: "memory");

        // O^T[m] += V^T @ P[m]^T
        __builtin_amdgcn_s_setprio(1);
#pragma unroll
        for (int ks = 0; ks < 2; ++ks) {
          bf16x8 vf[4], pf;
#pragma unroll
          for (int n2 = 0; n2 < 4; ++n2)
            vf[n2] = *reinterpret_cast<const bf16x8*>(
                &V_[(n2 * 16 + l15) * 64 + (((ks * 4 + g) ^ sw) * 8)]);
          pf = *reinterpret_cast<const bf16x8*>(&Pw[l15 * 64 + (((ks * 4 + g) ^ sw) * 8)]);
#pragma unroll
          for (int n2 = 0; n2 < 4; ++n2)
            o[m][n2] = __builtin_amdgcn_mfma_f32_16x16x32_bf16(vf[n2], pf, o[m][n2], 0, 0, 0);
        }
        __builtin_amdgcn_s_setprio(0);
      }
    }
    asm volatile("" ::: "memory");
    __builtin_amdgcn_s_barrier();
    cur ^= 1;
  }

  if (nch == 1) {
#pragma unroll
    for (int m = 0; m < 2; ++m) {
      float inv = 1.0f / lsum[m];
      int qg = qw + m * 16 + l15;
#pragma unroll
      for (int n2 = 0; n2 < 4; ++n2) {
        uint2 yk;
        yk.x = cvtpk(o[m][n2][0] * inv, o[m][n2][1] * inv);
        yk.y = cvtpk(o[m][n2][2] * inv, o[m][n2][3] * inv);
        *reinterpret_cast<uint2*>(&Y[(size_t)qg * C_DIM + h * 64 + n2 * 16 + g * 4]) = yk;
      }
    }
  } else {
    const int set = h * 72 + part_off(qb) + ck;
    unsigned short* po = part_ptr(partA, partB, set);
#pragma unroll
    for (int m = 0; m < 2; ++m) {
      int qL = wid * 32 + m * 16 + l15;
#pragma unroll
      for (int n2 = 0; n2 < 4; ++n2) {
        uint2 pk;
        pk.x = cvtpk(o[m][n2][0], o[m][n2][1]);
        pk.y = cvtpk(o[m][n2][2], o[m][n2][3]);
        *reinterpret_cast<uint2*>(&po[qL * 64 + n2 * 16 + g * 4]) = pk;
      }
      if (g == 0) {
        ml[(size_t)set * 256 + qL * 2] = mrow[m];
        ml[(size_t)set * 256 + qL * 2 + 1] = lsum[m];
      }
    }
  }
}

// ---------------- combine partials ----------------
__global__ __launch_bounds__(256)
void attn_combine(char* __restrict__ partA, char* __restrict__ partB,
                  const float* __restrict__ ml, unsigned short* __restrict__ Y) {
  const int qb = 8 + blockIdx.x;
  const int h = blockIdx.y;
  const int nch = qb / 8 + 1;
  const int set0 = h * 72 + part_off(qb);
  const int t = threadIdx.x;
  const int r = t >> 1, dh = (t & 1) * 32;

  float mi[4], li[4];
  float M = -1e30f;
  for (int i = 0; i < nch; ++i) {
    mi[i] = ml[(size_t)(set0 + i) * 256 + r * 2];
    li[i] = ml[(size_t)(set0 + i) * 256 + r * 2 + 1];
    M = fmaxf(M, mi[i]);
  }
  float L = 0.f;
  float O[32];
#pragma unroll
  for (int d = 0; d < 32; ++d) O[d] = 0.f;
  for (int i = 0; i < nch; ++i) {
    float w = __expf(mi[i] - M);
    L += li[i] * w;
    const unsigned short* po = part_ptr(partA, partB, set0 + i) + r * 64 + dh;
#pragma unroll
    for (int d4 = 0; d4 < 32; d4 += 4) {
      ushort4 v = *reinterpret_cast<const ushort4*>(po + d4);
      O[d4 + 0] += bf2f(v.x) * w;
      O[d4 + 1] += bf2f(v.y) * w;
      O[d4 + 2] += bf2f(v.z) * w;
      O[d4 + 3] += bf2f(v.w) * w;
    }
  }
  float inv = 1.0f / L;
  unsigned short* yp = Y + (size_t)(qb * 128 + r) * C_DIM + h * 64 + dh;
#pragma unroll
  for (int d4 = 0; d4 < 32; d4 += 4) {
    uint2 yk;
    yk.x = cvtpk(O[d4 + 0] * inv, O[d4 + 1] * inv);
    yk.y = cvtpk(O[d4 + 2] * inv, O[d4 + 3] * inv);
    *reinterpret_cast<uint2*>(yp + d4) = yk;
  }
}

// ---------------- launcher ----------------
extern "C" void kernel_launch(void* const* d_in, const int* in_sizes, int n_in,
                              void* d_out, int out_size, void* d_ws, size_t ws_size,
                              hipStream_t stream) {
  const float* x = (const float*)d_in[0];       // [4096][768]
  const float* w_attn = (const float*)d_in[1];  // [768][2304]
  const float* w_proj = (const float*)d_in[2];  // [768][768]
  float* out = (float*)d_out;                   // [4096][768] f32

  char* ws = (char*)d_ws;
  unsigned short* Xb   = (unsigned short*)(ws + 0);          // 6291456 B (dead after QKV -> part spill B)
  unsigned short* WaT  = (unsigned short*)(ws + 6291456);    // 3538944 B (dead after QKV -> ml)
  unsigned short* WpT  = (unsigned short*)(ws + 9830400);    // 1179648 B [768][768]
  unsigned short* Qb   = (unsigned short*)(ws + 11010048);   // 6291456 B [T][768]
  unsigned short* Kb   = (unsigned short*)(ws + 17301504);   // 6291456 B [T][768]
  unsigned short* Vt   = (unsigned short*)(ws + 23592960);   // 6291456 B [768][T]
  unsigned short* Yb   = (unsigned short*)(ws + 29884416);   // 6291456 B [T][768]

  char* partA = (char*)d_out;            // free during attention; overwritten by proj GEMM
  char* partB = (char*)ws;               // Xb region, dead after QKV GEMM
  float* mlp  = (float*)(ws + 6291456);  // WaT region, dead after QKV GEMM

  conv_bf16<<<(T_SEQ * C_DIM / 4 + 255) / 256, 256, 0, stream>>>(x, Xb, T_SEQ * C_DIM);
  transpose_bf16<<<dim3(2304 / 32, 768 / 32), 256, 0, stream>>>(w_attn, WaT, 768, 2304);
  transpose_bf16<<<dim3(768 / 32, 768 / 32), 256, 0, stream>>>(w_proj, WpT, 768, 768);

  gemm_bt<0><<<dim3(T_SEQ / 128, 2304 / 64), 256, 0, stream>>>(
      Xb, WaT, (void*)Qb, Kb, Vt, T_SEQ, 2304, C_DIM);

  attn_fwd<<<dim3(80, NH), 256, 0, stream>>>(Qb, Kb, Vt, Yb, partA, partB, mlp);
  attn_combine<<<dim3(24, NH), 256, 0, stream>>>(partA, partB, mlp, Yb);

  gemm_bt<1><<<dim3(T_SEQ / 128, C_DIM / 64), 256, 0, stream>>>(
      Yb, WpT, (void*)out, nullptr, nullptr, T_SEQ, C_DIM, C_DIM);
}

// Round 10
// 139.189 us; speedup vs baseline: 1.1594x; 1.0701x over previous
//
#include <hip/hip_runtime.h>

// Causal self-attention: B=1, T=4096, C=768, H=12, hd=64
// f32 in/out, bf16 MFMA compute internally. Flash-decoding s-split.
// R10: attn inner loop = exact R6 (P-split regressed: R9). New: LPT dispatch
// (grid (NH,80), long chunks first across all heads) + exp2-domain softmax
// (log2e folded into Q prescale). GEMM 128x64 kept from R9.

typedef short bf16x8 __attribute__((ext_vector_type(8)));
typedef float f32x4 __attribute__((ext_vector_type(4)));

#define T_SEQ 4096
#define C_DIM 768
#define NH 12
#define HD 64

__device__ __forceinline__ unsigned short f2bf(float f) {
  union { float f; unsigned u; } v; v.f = f;
  unsigned r = v.u + 0x7FFFu + ((v.u >> 16) & 1u);
  return (unsigned short)(r >> 16);
}
__device__ __forceinline__ float bf2f(unsigned short u) {
  union { unsigned u; float f; } v; v.u = ((unsigned)u) << 16;
  return v.f;
}
__device__ __forceinline__ unsigned cvtpk(float a, float b) {
  unsigned r;
  asm("v_cvt_pk_bf16_f32 %0, %1, %2" : "=v"(r) : "v"(a), "v"(b));
  return r;
}
#define E2(x) __builtin_amdgcn_exp2f(x)

#define GLD16(g, l) __builtin_amdgcn_global_load_lds( \
    (const __attribute__((address_space(1))) void*)(g), \
    (__attribute__((address_space(3))) void*)(l), 16, 0, 0)

// ---------------- f32 -> bf16 convert (vectorized) ----------------
__global__ void conv_bf16(const float* __restrict__ in, unsigned short* __restrict__ out, int n) {
  int i = (blockIdx.x * blockDim.x + threadIdx.x) * 4;
  if (i + 3 < n) {
    float4 v = *reinterpret_cast<const float4*>(in + i);
    ushort4 o;
    o.x = f2bf(v.x); o.y = f2bf(v.y); o.z = f2bf(v.z); o.w = f2bf(v.w);
    *reinterpret_cast<ushort4*>(out + i) = o;
  }
}

// ---------------- transpose f32 [R][Cc] -> bf16 [Cc][R] ----------------
__global__ void transpose_bf16(const float* __restrict__ in, unsigned short* __restrict__ out,
                               int R, int Cc) {
  __shared__ float tile[32][33];
  int bx = blockIdx.x * 32;
  int by = blockIdx.y * 32;
  int tx = threadIdx.x & 31, ty = threadIdx.x >> 5;
#pragma unroll
  for (int i = 0; i < 32; i += 8)
    tile[ty + i][tx] = in[(size_t)(by + ty + i) * Cc + bx + tx];
  __syncthreads();
#pragma unroll
  for (int i = 0; i < 32; i += 8)
    out[(size_t)(bx + ty + i) * R + by + tx] = f2bf(tile[tx][ty + i]);
}

// ---------------- BT-GEMM: A[M][K] bf16 @ Bt[N][K] bf16 ----------------
// Tile 128x64 (R9: more blocks -> TLP; LDS 24KB -> 6 blocks/CU).
template <int MODE>
__global__ __launch_bounds__(256, 2)
void gemm_bt(const unsigned short* __restrict__ A,
             const unsigned short* __restrict__ Bt,
             void* __restrict__ out0,
             unsigned short* __restrict__ Kout,
             unsigned short* __restrict__ Vt,
             int M, int N, int K) {
  __shared__ __align__(16) unsigned short As[128 * 64];
  __shared__ __align__(16) unsigned short Bs[64 * 64];
  const int bm = blockIdx.x, bn = blockIdx.y;
  const int tid = threadIdx.x;
  const int wid = tid >> 6, lane = tid & 63;
  const int wr = wid >> 1, wc = wid & 1;
  const int lr = lane & 15;
  const int lk8 = (lane >> 4) * 8;
  const int rsub = lane >> 3, csub = (lane & 7) * 8;

  f32x4 acc[4][2] = {};

  const int nk = K / 64;
  for (int kt = 0; kt < nk; ++kt) {
    __syncthreads();
    {
      const unsigned short* gA = A + (size_t)(bm * 128) * K + kt * 64;
      const unsigned short* gB = Bt + (size_t)(bn * 64) * K + kt * 64;
#pragma unroll
      for (int c = 0; c < 4; ++c) {
        int seg = wid * 4 + c;            // A: 16 segs of 1KB
        int row = seg * 8 + rsub;
        GLD16(gA + (size_t)row * K + csub, (char*)As + seg * 1024);
      }
#pragma unroll
      for (int c = 0; c < 2; ++c) {
        int seg = wid * 2 + c;            // B: 8 segs of 1KB
        int row = seg * 8 + rsub;
        GLD16(gB + (size_t)row * K + csub, (char*)Bs + seg * 1024);
      }
    }
    __syncthreads();
#pragma unroll
    for (int kk = 0; kk < 2; ++kk) {
      bf16x8 a[4], b[2];
      int lk = kk * 32 + lk8;
#pragma unroll
      for (int m = 0; m < 4; ++m)
        a[m] = *reinterpret_cast<const bf16x8*>(&As[(wr * 64 + m * 16 + lr) * 64 + lk]);
#pragma unroll
      for (int n = 0; n < 2; ++n)
        b[n] = *reinterpret_cast<const bf16x8*>(&Bs[(wc * 32 + n * 16 + lr) * 64 + lk]);
#pragma unroll
      for (int m = 0; m < 4; ++m)
#pragma unroll
        for (int n = 0; n < 2; ++n)
          acc[m][n] = __builtin_amdgcn_mfma_f32_16x16x32_bf16(a[m], b[n], acc[m][n], 0, 0, 0);
    }
  }

  const int row0 = bm * 128 + wr * 64;
  const int col0 = bn * 64 + wc * 32;
#pragma unroll
  for (int m = 0; m < 4; ++m)
#pragma unroll
    for (int n = 0; n < 2; ++n)
#pragma unroll
      for (int j = 0; j < 4; ++j) {
        int r = row0 + m * 16 + (lane >> 4) * 4 + j;
        int c = col0 + n * 16 + (lane & 15);
        float v = acc[m][n][j];
        if (MODE == 0) {
          if (c < 768)  // Q pre-scaled by (1/8)*log2(e) for exp2-domain softmax
            ((unsigned short*)out0)[(size_t)r * 768 + c] = f2bf(v * 0.180336884f);
          else if (c < 1536)
            Kout[(size_t)r * 768 + (c - 768)] = f2bf(v);
          else
            Vt[(size_t)(c - 1536) * M + r] = f2bf(v);
        } else {
          ((float*)out0)[(size_t)r * N + c] = v;
        }
      }
}

// ---------------- attention helpers ----------------
__device__ __forceinline__ void stage_kv(const unsigned short* __restrict__ Kb,
                                         const unsigned short* __restrict__ Vt,
                                         unsigned short* Kbuf, unsigned short* Vbuf,
                                         int h, int st, int wid, int lane) {
  const int cg = lane & 7, rsub = (lane >> 3) & 7;
  const unsigned short* gK = Kb + (size_t)(st * 64) * C_DIM + h * 64;
  const unsigned short* gV = Vt + (size_t)(h * 64) * T_SEQ + st * 64;
#pragma unroll
  for (int c = 0; c < 2; ++c) {
    int seg = wid * 2 + c;
    int row = seg * 8 + rsub;
    GLD16(gK + (size_t)row * C_DIM + (cg ^ rsub) * 8, (char*)Kbuf + seg * 1024);
    GLD16(gV + (size_t)row * T_SEQ + (cg ^ rsub) * 8, (char*)Vbuf + seg * 1024);
  }
}

// partial set id: per head 72 sets (qb>=8 only). offset within head:
__device__ __forceinline__ int part_off(int qb) {
  return (qb < 16) ? (qb - 8) * 2 : (qb < 24) ? 16 + (qb - 16) * 3 : 40 + (qb - 24) * 4;
}
__device__ __forceinline__ unsigned short* part_ptr(char* pA, char* pB, int set) {
  return (set < 768) ? (unsigned short*)(pA + (size_t)set * 16384)
                     : (unsigned short*)(pB + (size_t)(set - 768) * 16384);
}

// ---------------- flash attention (causal, swapped QK^T, s-chunked) ----------------
// grid = (NH, 80): x = head (fastest dispatch dim) so the qb-descending chunk
// slots in y dispatch longest-first across ALL heads (LPT makespan).
// global_load_lds staging (reg-staging spills: R4/R5); min-waves 3.
__global__ __launch_bounds__(256, 3)
void attn_fwd(const unsigned short* __restrict__ Qb,
              const unsigned short* __restrict__ Kb,
              const unsigned short* __restrict__ Vt,
              unsigned short* __restrict__ Y,
              char* __restrict__ partA, char* __restrict__ partB,
              float* __restrict__ ml) {
  __shared__ __align__(16) unsigned short Ks[2][64 * 64];
  __shared__ __align__(16) unsigned short Vs[2][64 * 64];  // [d][s]
  __shared__ __align__(16) unsigned short Ps[4][32 * 64];

  const int h = blockIdx.x;
  int qb = 0, ck = 0;
  {
    int idx = blockIdx.y;
    for (int q = 31; q >= 0; --q) {
      int nc = q / 8 + 1;
      if (idx < nc) { qb = q; ck = idx; break; }
      idx -= nc;
    }
  }
  const int nch = qb / 8 + 1;
  const int q0 = qb * 128;
  const int nst_total = q0 / 64 + 2;
  const int st0 = ck * 16;
  const int st1 = (st0 + 16 < nst_total) ? st0 + 16 : nst_total;

  const int tid = threadIdx.x;
  const int wid = tid >> 6, lane = tid & 63;
  const int l15 = lane & 15, g = lane >> 4;
  const int sw = l15 & 7;
  const int qw = q0 + wid * 32;

  bf16x8 qf[2][2];
#pragma unroll
  for (int m = 0; m < 2; ++m)
#pragma unroll
    for (int kk = 0; kk < 2; ++kk)
      qf[m][kk] = *reinterpret_cast<const bf16x8*>(
          &Qb[(size_t)(qw + m * 16 + l15) * C_DIM + h * 64 + kk * 32 + g * 8]);

  f32x4 o[2][4] = {};  // O^T fragments: row=d, col=q
  float mrow[2] = {-1e30f, -1e30f};
  float lsum[2] = {0.f, 0.f};

  stage_kv(Kb, Vt, Ks[0], Vs[0], h, st0, wid, lane);
  int cur = 0;

  for (int st = st0; st < st1; ++st) {
    if (st + 1 < st1) {
      stage_kv(Kb, Vt, Ks[cur ^ 1], Vs[cur ^ 1], h, st + 1, wid, lane);
      asm volatile("s_waitcnt vmcnt(4)" ::: "memory");  // cur tile's 4 loads done
    } else {
      asm volatile("s_waitcnt vmcnt(0)" ::: "memory");
    }
    __builtin_amdgcn_s_barrier();

    const bool active = (st * 64) <= (qw + 31);
    if (active) {
      const unsigned short* K_ = Ks[cur];
      const unsigned short* V_ = Vs[cur];

      // S^T = K @ Q^T  (S in log2 domain: Q pre-scaled by 0.125*log2e)
      f32x4 sT[2][4] = {};
      __builtin_amdgcn_s_setprio(1);
#pragma unroll
      for (int kk = 0; kk < 2; ++kk) {
        bf16x8 kf[4];
#pragma unroll
        for (int n = 0; n < 4; ++n)
          kf[n] = *reinterpret_cast<const bf16x8*>(
              &K_[(n * 16 + l15) * 64 + (((kk * 4 + g) ^ sw) * 8)]);
#pragma unroll
        for (int m = 0; m < 2; ++m)
#pragma unroll
          for (int n = 0; n < 4; ++n)
            sT[m][n] = __builtin_amdgcn_mfma_f32_16x16x32_bf16(kf[n], qf[m][kk], sT[m][n], 0, 0, 0);
      }
      __builtin_amdgcn_s_setprio(0);

      unsigned short* Pw = Ps[wid];
#pragma unroll
      for (int m = 0; m < 2; ++m) {
        float vmax = -1e30f;
        if (st * 64 + 63 <= qw + m * 16) {
          // fully unmasked tile for this row-block (wave-uniform branch)
#pragma unroll
          for (int n = 0; n < 4; ++n)
#pragma unroll
            for (int jj = 0; jj < 4; ++jj) vmax = fmaxf(vmax, sT[m][n][jj]);
        } else {
          const int bound = (qw + m * 16 + l15) - st * 64;
#pragma unroll
          for (int n = 0; n < 4; ++n)
#pragma unroll
            for (int jj = 0; jj < 4; ++jj) {
              int sl = n * 16 + g * 4 + jj;
              float v = sT[m][n][jj];
              v = (sl <= bound) ? v : -1e30f;
              sT[m][n][jj] = v;
              vmax = fmaxf(vmax, v);
            }
        }
        vmax = fmaxf(vmax, __shfl_xor(vmax, 16, 64));
        vmax = fmaxf(vmax, __shfl_xor(vmax, 32, 64));
        // defer-rescale (T13): keep old max while growth <= 8 (P bounded by 2^8)
        const bool defer = (__all(vmax <= mrow[m] + 8.0f) != 0);
        const float mnew = defer ? mrow[m] : fmaxf(mrow[m], vmax);
        float ps = 0.f;
#pragma unroll
        for (int n = 0; n < 4; ++n)
#pragma unroll
          for (int jj = 0; jj < 4; ++jj) {
            float p = E2(sT[m][n][jj] - mnew);
            sT[m][n][jj] = p;
            ps += p;
          }
        ps += __shfl_xor(ps, 16, 64);
        ps += __shfl_xor(ps, 32, 64);
        if (defer) {
          lsum[m] += ps;
        } else {
          float alpha = E2(mrow[m] - mnew);
          lsum[m] = lsum[m] * alpha + ps;
          mrow[m] = mnew;
#pragma unroll
          for (int n2 = 0; n2 < 4; ++n2) o[m][n2] *= alpha;
        }
#pragma unroll
        for (int n = 0; n < 4; ++n) {
          uint2 pw;
          pw.x = cvtpk(sT[m][n][0], sT[m][n][1]);
          pw.y = cvtpk(sT[m][n][2], sT[m][n][3]);
          *reinterpret_cast<uint2*>(
              &Pw[(m * 16 + l15) * 64 + (((n * 2 + (g >> 1)) ^ sw) * 8) + (g & 1) * 4]) = pw;
        }
      }
      asm volatile("s_waitcnt lgkmcnt(0)" ::: "memory");

      // O^T += V^T @ P^T
      __builtin_amdgcn_s_setprio(1);
#pragma unroll
      for (int ks = 0; ks < 2; ++ks) {
        bf16x8 vf[4], pf[2];
#pragma unroll
        for (int n2 = 0; n2 < 4; ++n2)
          vf[n2] = *reinterpret_cast<const bf16x8*>(
              &V_[(n2 * 16 + l15) * 64 + (((ks * 4 + g) ^ sw) * 8)]);
#pragma unroll
        for (int m = 0; m < 2; ++m)
          pf[m] = *reinterpret_cast<const bf16x8*>(
              &Pw[(m * 16 + l15) * 64 + (((ks * 4 + g) ^ sw) * 8)]);
#pragma unroll
        for (int m = 0; m < 2; ++m)
#pragma unroll
          for (int n2 = 0; n2 < 4; ++n2)
            o[m][n2] = __builtin_amdgcn_mfma_f32_16x16x32_bf16(vf[n2], pf[m], o[m][n2], 0, 0, 0);
      }
      __builtin_amdgcn_s_setprio(0);
    }
    asm volatile("" ::: "memory");
    __builtin_amdgcn_s_barrier();
    cur ^= 1;
  }

  if (nch == 1) {
#pragma unroll
    for (int m = 0; m < 2; ++m) {
      float inv = 1.0f / lsum[m];
      int qg = qw + m * 16 + l15;
#pragma unroll
      for (int n2 = 0; n2 < 4; ++n2) {
        uint2 yk;
        yk.x = cvtpk(o[m][n2][0] * inv, o[m][n2][1] * inv);
        yk.y = cvtpk(o[m][n2][2] * inv, o[m][n2][3] * inv);
        *reinterpret_cast<uint2*>(&Y[(size_t)qg * C_DIM + h * 64 + n2 * 16 + g * 4]) = yk;
      }
    }
  } else {
    const int set = h * 72 + part_off(qb) + ck;
    unsigned short* po = part_ptr(partA, partB, set);
#pragma unroll
    for (int m = 0; m < 2; ++m) {
      int qL = wid * 32 + m * 16 + l15;
#pragma unroll
      for (int n2 = 0; n2 < 4; ++n2) {
        uint2 pk;
        pk.x = cvtpk(o[m][n2][0], o[m][n2][1]);
        pk.y = cvtpk(o[m][n2][2], o[m][n2][3]);
        *reinterpret_cast<uint2*>(&po[qL * 64 + n2 * 16 + g * 4]) = pk;
      }
      if (g == 0) {
        ml[(size_t)set * 256 + qL * 2] = mrow[m];
        ml[(size_t)set * 256 + qL * 2 + 1] = lsum[m];
      }
    }
  }
}

// ---------------- combine partials (exp2 domain) ----------------
__global__ __launch_bounds__(256)
void attn_combine(char* __restrict__ partA, char* __restrict__ partB,
                  const float* __restrict__ ml, unsigned short* __restrict__ Y) {
  const int qb = 8 + blockIdx.x;
  const int h = blockIdx.y;
  const int nch = qb / 8 + 1;
  const int set0 = h * 72 + part_off(qb);
  const int t = threadIdx.x;
  const int r = t >> 1, dh = (t & 1) * 32;

  float mi[4], li[4];
  float M = -1e30f;
  for (int i = 0; i < nch; ++i) {
    mi[i] = ml[(size_t)(set0 + i) * 256 + r * 2];
    li[i] = ml[(size_t)(set0 + i) * 256 + r * 2 + 1];
    M = fmaxf(M, mi[i]);
  }
  float L = 0.f;
  float O[32];
#pragma unroll
  for (int d = 0; d < 32; ++d) O[d] = 0.f;
  for (int i = 0; i < nch; ++i) {
    float w = E2(mi[i] - M);
    L += li[i] * w;
    const unsigned short* po = part_ptr(partA, partB, set0 + i) + r * 64 + dh;
#pragma unroll
    for (int d4 = 0; d4 < 32; d4 += 4) {
      ushort4 v = *reinterpret_cast<const ushort4*>(po + d4);
      O[d4 + 0] += bf2f(v.x) * w;
      O[d4 + 1] += bf2f(v.y) * w;
      O[d4 + 2] += bf2f(v.z) * w;
      O[d4 + 3] += bf2f(v.w) * w;
    }
  }
  float inv = 1.0f / L;
  unsigned short* yp = Y + (size_t)(qb * 128 + r) * C_DIM + h * 64 + dh;
#pragma unroll
  for (int d4 = 0; d4 < 32; d4 += 4) {
    uint2 yk;
    yk.x = cvtpk(O[d4 + 0] * inv, O[d4 + 1] * inv);
    yk.y = cvtpk(O[d4 + 2] * inv, O[d4 + 3] * inv);
    *reinterpret_cast<uint2*>(yp + d4) = yk;
  }
}

// ---------------- launcher ----------------
extern "C" void kernel_launch(void* const* d_in, const int* in_sizes, int n_in,
                              void* d_out, int out_size, void* d_ws, size_t ws_size,
                              hipStream_t stream) {
  const float* x = (const float*)d_in[0];       // [4096][768]
  const float* w_attn = (const float*)d_in[1];  // [768][2304]
  const float* w_proj = (const float*)d_in[2];  // [768][768]
  float* out = (float*)d_out;                   // [4096][768] f32

  char* ws = (char*)d_ws;
  unsigned short* Xb   = (unsigned short*)(ws + 0);          // 6291456 B (dead after QKV -> part spill B)
  unsigned short* WaT  = (unsigned short*)(ws + 6291456);    // 3538944 B (dead after QKV -> ml)
  unsigned short* WpT  = (unsigned short*)(ws + 9830400);    // 1179648 B [768][768]
  unsigned short* Qb   = (unsigned short*)(ws + 11010048);   // 6291456 B [T][768]
  unsigned short* Kb   = (unsigned short*)(ws + 17301504);   // 6291456 B [T][768]
  unsigned short* Vt   = (unsigned short*)(ws + 23592960);   // 6291456 B [768][T]
  unsigned short* Yb   = (unsigned short*)(ws + 29884416);   // 6291456 B [T][768]

  char* partA = (char*)d_out;            // free during attention; overwritten by proj GEMM
  char* partB = (char*)ws;               // Xb region, dead after QKV GEMM
  float* mlp  = (float*)(ws + 6291456);  // WaT region, dead after QKV GEMM

  conv_bf16<<<(T_SEQ * C_DIM / 4 + 255) / 256, 256, 0, stream>>>(x, Xb, T_SEQ * C_DIM);
  transpose_bf16<<<dim3(2304 / 32, 768 / 32), 256, 0, stream>>>(w_attn, WaT, 768, 2304);
  transpose_bf16<<<dim3(768 / 32, 768 / 32), 256, 0, stream>>>(w_proj, WpT, 768, 768);

  gemm_bt<0><<<dim3(T_SEQ / 128, 2304 / 64), 256, 0, stream>>>(
      Xb, WaT, (void*)Qb, Kb, Vt, T_SEQ, 2304, C_DIM);

  attn_fwd<<<dim3(NH, 80), 256, 0, stream>>>(Qb, Kb, Vt, Yb, partA, partB, mlp);
  attn_combine<<<dim3(24, NH), 256, 0, stream>>>(partA, partB, mlp, Yb);

  gemm_bt<1><<<dim3(T_SEQ / 128, C_DIM / 64), 256, 0, stream>>>(
      Yb, WpT, (void*)out, nullptr, nullptr, T_SEQ, C_DIM, C_DIM);
}